// Round 1
// baseline (881.573 us; speedup 1.0000x reference)
//
#include <hip/hip_runtime.h>

// StructuredElmanCell: per-scalar-state recurrence chains.
// H[b,h,n,p] <- silu(alpha[t,b,h]*H + sum_r B[t,b,h,n,r]*X[t,b,h,p,r])
// y[t,b,h*HD+p] = sum_n H_new ; out = y*silu(z+y)
// One thread per (b,h,p,n). Wave = 2 p x 32 n -> n-reduction via shfl_xor.

namespace {
constexpr int T  = 1024;
constexpr int BS = 4;
constexpr int NH = 16;
constexpr int DS = 32;
constexpr int HD = 128;
constexpr int R  = 8;
constexpr int DI = NH * HD;              // 2048
constexpr int B_STRIDE_T = BS * NH * DS * R;   // 16384 floats per t
constexpr int X_STRIDE_T = BS * NH * HD * R;   // 65536 floats per t
constexpr int A_STRIDE_T = BS * NH;            // 64
constexpr int Z_STRIDE_T = BS * DI;            // 8192 (also out per-t stride)

__device__ __forceinline__ float fast_silu(float x) {
    // x * sigmoid(x) = x / (1 + exp(-x))
    return x / (1.0f + __expf(-x));
}

__global__ __launch_bounds__(256, 4)
void elman_scan_kernel(const float* __restrict__ B_,
                       const float* __restrict__ X_,
                       const float* __restrict__ ar_,
                       const float* __restrict__ ab_,
                       const float* __restrict__ z_,
                       const float* __restrict__ H0_,
                       float* __restrict__ out_,
                       float* __restrict__ Hf_)
{
    const int tid  = blockIdx.x * 256 + threadIdx.x;
    const int lane = threadIdx.x & 63;
    const int n    = lane & 31;        // state row within DS
    const int pl   = lane >> 5;        // 0/1: which p of this wave
    const int w    = tid >> 6;         // global wave id, 0..4095
    const int bh   = w >> 6;           // 0..63  (64 waves per (b,h))
    const int wp   = w & 63;           // wave's p-pair index
    const int p    = wp * 2 + pl;      // 0..127
    const int h    = bh & (NH - 1);
    const int b    = bh >> 4;

    // element-t base pointers for this thread
    const float* Bp = B_  + (size_t)bh * DS * R + (size_t)n * R;
    const float* Xp = X_  + (size_t)bh * HD * R + (size_t)p * R;
    const float* ap = ar_ + bh;
    const float* zp = z_  + (size_t)b * DI + (size_t)h * HD + p;
    const float  ab = ab_[h];

    float H = H0_[((size_t)bh * DS + n) * HD + p];

    // prime the pipeline: load t=0
    float4 cb0 = *(const float4*)(Bp);
    float4 cb1 = *(const float4*)(Bp + 4);
    float4 cx0 = *(const float4*)(Xp);
    float4 cx1 = *(const float4*)(Xp + 4);
    float  car = *ap;
    float  cz  = *zp;

    float* outp = out_ + (size_t)b * DI + (size_t)h * HD + p;

    for (int t = 0; t < T; ++t) {
        // ---- prefetch t+1 (clamped on last iter to avoid OOB) ----
        const bool last = (t == T - 1);
        const float* Bq = last ? Bp : Bp + B_STRIDE_T;
        const float* Xq = last ? Xp : Xp + X_STRIDE_T;
        const float* aq = last ? ap : ap + A_STRIDE_T;
        const float* zq = last ? zp : zp + Z_STRIDE_T;
        float4 nb0 = *(const float4*)(Bq);
        float4 nb1 = *(const float4*)(Bq + 4);
        float4 nx0 = *(const float4*)(Xq);
        float4 nx1 = *(const float4*)(Xq + 4);
        float  nar = *aq;
        float  nz  = *zq;

        // ---- rank-8 update: u = sum_r B[n,r]*X[p,r] ----
        float u =      cb0.x * cx0.x;
        u = fmaf(cb0.y, cx0.y, u);
        u = fmaf(cb0.z, cx0.z, u);
        u = fmaf(cb0.w, cx0.w, u);
        u = fmaf(cb1.x, cx1.x, u);
        u = fmaf(cb1.y, cx1.y, u);
        u = fmaf(cb1.z, cx1.z, u);
        u = fmaf(cb1.w, cx1.w, u);

        // alpha = sigmoid(-softplus(x)) == 1/(2+exp(x))  (exact identity)
        const float alpha = 1.0f / (2.0f + __expf(car + ab));

        const float hpre = fmaf(alpha, H, u);
        H = fast_silu(hpre);

        // ---- y = sum over 32 n-lanes (butterfly within 32-lane half) ----
        float y = H;
        y += __shfl_xor(y, 1, 64);
        y += __shfl_xor(y, 2, 64);
        y += __shfl_xor(y, 4, 64);
        y += __shfl_xor(y, 8, 64);
        y += __shfl_xor(y, 16, 64);

        // ---- gated output ----
        const float res = y * fast_silu(cz + y);
        if (n == 0) {
            outp[(size_t)t * Z_STRIDE_T] = res;
        }

        // rotate double-buffer
        cb0 = nb0; cb1 = nb1; cx0 = nx0; cx1 = nx1; car = nar; cz = nz;
        Bp = Bq; Xp = Xq; ap = aq; zp = zq;
    }

    // H_final [BS,NH,DS,HD]
    Hf_[((size_t)bh * DS + n) * HD + p] = H;
}
} // namespace

extern "C" void kernel_launch(void* const* d_in, const int* in_sizes, int n_in,
                              void* d_out, int out_size, void* d_ws, size_t ws_size,
                              hipStream_t stream) {
    const float* B_proj     = (const float*)d_in[0];
    const float* X_proj     = (const float*)d_in[1];
    const float* alpha_raw  = (const float*)d_in[2];
    const float* alpha_bias = (const float*)d_in[3];
    const float* z          = (const float*)d_in[4];
    const float* H0         = (const float*)d_in[5];

    float* out = (float*)d_out;                       // [T,BS,DI]
    float* Hf  = out + (size_t)T * BS * DI;           // [BS,NH,DS,HD]

    // 262144 threads: one per (b,h,p,n) chain. 1024 blocks x 256.
    elman_scan_kernel<<<1024, 256, 0, stream>>>(B_proj, X_proj, alpha_raw,
                                                alpha_bias, z, H0, out, Hf);
}

// Round 2
// 650.324 us; speedup vs baseline: 1.3556x; 1.3556x over previous
//
#include <hip/hip_runtime.h>

// StructuredElmanCell — per-scalar-state recurrence chains.
// H[b,h,n,p] <- silu(alpha[t,b,h]*H + sum_r B[t,b,h,n,r]*X[t,b,h,p,r])
// y[t,b,h*HD+p] = sum_n H_new ; out = y*silu(z+y)  (gate applied in pass 2)
// One thread per (b,h,p,n). Wave = 2 p x 32 n -> n-reduction via DPP prefix.

namespace {
constexpr int T  = 1024;
constexpr int BS = 4;
constexpr int NH = 16;
constexpr int DS = 32;
constexpr int HD = 128;
constexpr int R  = 8;
constexpr int DI = NH * HD;                    // 2048
constexpr int B_STRIDE_T = BS * NH * DS * R;   // 16384 floats per t
constexpr int X_STRIDE_T = BS * NH * HD * R;   // 65536 floats per t
constexpr int A_STRIDE_T = BS * NH;            // 64
constexpr int Z_STRIDE_T = BS * DI;            // 8192 (out per-t stride)

constexpr float LOG2E = 1.4426950408889634f;

__device__ __forceinline__ float fast_exp(float x) {
    return __builtin_amdgcn_exp2f(x * LOG2E);          // v_exp_f32 = 2^x
}
__device__ __forceinline__ float fast_silu(float x) {
    // x * sigmoid(x) = x * rcp(1 + exp(-x)) — 3 VALU + 2 trans, no fdiv
    float e = __builtin_amdgcn_exp2f(x * -LOG2E);
    return x * __builtin_amdgcn_rcpf(1.0f + e);
}

// y += lane-shifted y via DPP (full-rate VALU, no LDS pipe)
template<int CTRL>
__device__ __forceinline__ float dpp_add(float v) {
    int s = __builtin_amdgcn_update_dpp(0, __float_as_int(v), CTRL, 0xF, 0xF, true);
    return v + __int_as_float(s);
}
// Sum over each 32-lane half; total lands in lanes 31 and 63.
__device__ __forceinline__ float group32_sum_to_lane31(float y) {
    y = dpp_add<0x111>(y);   // row_shr:1
    y = dpp_add<0x112>(y);   // row_shr:2
    y = dpp_add<0x114>(y);   // row_shr:4
    y = dpp_add<0x118>(y);   // row_shr:8  -> lane15/31/47/63 hold row-of-16 sums
    y = dpp_add<0x142>(y);   // row_bcast15 -> lane31 += lane15, lane63 += lane47
    return y;
}

// ---------------- pass 0: alpha = 1/(2+exp(ar+ab)) -------------------------
__global__ __launch_bounds__(256)
void alpha_kernel(const float* __restrict__ ar_, const float* __restrict__ ab_,
                  float* __restrict__ alpha_) {
    int i = blockIdx.x * 256 + threadIdx.x;          // [T,BS,NH] flat
    float v = ar_[i] + ab_[i & (NH - 1)];
    // sigmoid(-softplus(v)) == 1/(2+exp(v)) exactly
    alpha_[i] = __builtin_amdgcn_rcpf(2.0f + fast_exp(v));
}

// ---------------- pass 1: the scan, emits raw y sums -----------------------
template<bool PRE>
__global__ __launch_bounds__(256, 4)
void elman_scan_kernel(const float* __restrict__ B_,
                       const float* __restrict__ X_,
                       const float* __restrict__ a_,   // PRE? alpha : alpha_raw
                       const float* __restrict__ ab_,
                       const float* __restrict__ H0_,
                       float* __restrict__ y_,         // [T,BS,DI] raw sums
                       float* __restrict__ Hf_)
{
    const int tid  = blockIdx.x * 256 + threadIdx.x;
    const int lane = threadIdx.x & 63;
    const int n    = lane & 31;        // state row within DS
    const int pl   = lane >> 5;        // which p of this wave
    const int w    = tid >> 6;         // global wave id, 0..4095
    const int bh   = w >> 6;           // 64 waves per (b,h)
    const int wp   = w & 63;
    const int p    = wp * 2 + pl;      // 0..127
    const int h    = bh & (NH - 1);
    const int b    = bh >> 4;
    const bool owner = (n == 31);

    const float ab = PRE ? 0.0f : ab_[h];

    float H = H0_[((size_t)bh * DS + n) * HD + p];

    // dual pointer sets (even/odd t), each advanced by 2 strides per iter
    const float* BpA = B_ + (size_t)bh * DS * R + (size_t)n * R;
    const float* XpA = X_ + (size_t)bh * HD * R + (size_t)p * R;
    const float* apA = a_ + bh;
    const float* BpB = BpA + B_STRIDE_T;
    const float* XpB = XpA + X_STRIDE_T;
    const float* apB = apA + A_STRIDE_T;
    float* ypA = y_ + (size_t)b * DI + (size_t)h * HD + p;
    float* ypB = ypA + Z_STRIDE_T;

    // prime stages: A=t0, B=t1
    float4 ab0 = *(const float4*)(BpA);
    float4 ab1 = *(const float4*)(BpA + 4);
    float4 ax0 = *(const float4*)(XpA);
    float4 ax1 = *(const float4*)(XpA + 4);
    float  aal = *apA;
    float4 bb0 = *(const float4*)(BpB);
    float4 bb1 = *(const float4*)(BpB + 4);
    float4 bx0 = *(const float4*)(XpB);
    float4 bx1 = *(const float4*)(XpB + 4);
    float  bal = *apB;

    auto step = [&](float4 cb0, float4 cb1, float4 cx0, float4 cx1,
                    float ca, float* outp) {
        // rank-8 update, two accumulator chains
        float u0 =      cb0.x * cx0.x;
        u0 = fmaf(cb0.z, cx0.z, u0);
        u0 = fmaf(cb1.x, cx1.x, u0);
        u0 = fmaf(cb1.z, cx1.z, u0);
        float u1 =      cb0.y * cx0.y;
        u1 = fmaf(cb0.w, cx0.w, u1);
        u1 = fmaf(cb1.y, cx1.y, u1);
        u1 = fmaf(cb1.w, cx1.w, u1);
        float alpha = PRE ? ca
                          : __builtin_amdgcn_rcpf(2.0f + fast_exp(ca + ab));
        float hpre = fmaf(alpha, H, u0 + u1);
        H = fast_silu(hpre);
        float y = group32_sum_to_lane31(H);
        if (owner) *outp = y;
    };

    for (int t = 0; t < T - 2; t += 2) {
        // advance A set to t+2, issue prefetch before consuming stage A
        BpA += 2 * B_STRIDE_T; XpA += 2 * X_STRIDE_T; apA += 2 * A_STRIDE_T;
        float4 nb0 = *(const float4*)(BpA);
        float4 nb1 = *(const float4*)(BpA + 4);
        float4 nx0 = *(const float4*)(XpA);
        float4 nx1 = *(const float4*)(XpA + 4);
        float  nal = *apA;

        step(ab0, ab1, ax0, ax1, aal, ypA);
        ypA += 2 * Z_STRIDE_T;

        BpB += 2 * B_STRIDE_T; XpB += 2 * X_STRIDE_T; apB += 2 * A_STRIDE_T;
        float4 mb0 = *(const float4*)(BpB);
        float4 mb1 = *(const float4*)(BpB + 4);
        float4 mx0 = *(const float4*)(XpB);
        float4 mx1 = *(const float4*)(XpB + 4);
        float  mal = *apB;

        step(bb0, bb1, bx0, bx1, bal, ypB);
        ypB += 2 * Z_STRIDE_T;

        ab0 = nb0; ab1 = nb1; ax0 = nx0; ax1 = nx1; aal = nal;
        bb0 = mb0; bb1 = mb1; bx0 = mx0; bx1 = mx1; bal = mal;
    }
    // peeled final two timesteps (t = T-2, T-1)
    step(ab0, ab1, ax0, ax1, aal, ypA);
    step(bb0, bb1, bx0, bx1, bal, ypB);

    Hf_[((size_t)bh * DS + n) * HD + p] = H;
}

// ---------------- pass 2: out = y * silu(z + y), in place ------------------
__global__ __launch_bounds__(256)
void gate_kernel(float* __restrict__ y_, const float* __restrict__ z_) {
    int i = blockIdx.x * 256 + threadIdx.x;          // float4 index
    float4 y4 = ((const float4*)y_)[i];
    float4 z4 = ((const float4*)z_)[i];
    float4 o;
    o.x = y4.x * fast_silu(z4.x + y4.x);
    o.y = y4.y * fast_silu(z4.y + y4.y);
    o.z = y4.z * fast_silu(z4.z + y4.z);
    o.w = y4.w * fast_silu(z4.w + y4.w);
    ((float4*)y_)[i] = o;
}
} // namespace

extern "C" void kernel_launch(void* const* d_in, const int* in_sizes, int n_in,
                              void* d_out, int out_size, void* d_ws, size_t ws_size,
                              hipStream_t stream) {
    const float* B_proj     = (const float*)d_in[0];
    const float* X_proj     = (const float*)d_in[1];
    const float* alpha_raw  = (const float*)d_in[2];
    const float* alpha_bias = (const float*)d_in[3];
    const float* z          = (const float*)d_in[4];
    const float* H0         = (const float*)d_in[5];

    float* out = (float*)d_out;                       // [T,BS,DI] then Hf
    float* Hf  = out + (size_t)T * BS * DI;

    const size_t alpha_bytes = (size_t)T * BS * NH * sizeof(float);
    if (ws_size >= alpha_bytes) {
        float* aw = (float*)d_ws;
        alpha_kernel<<<T * BS * NH / 256, 256, 0, stream>>>(alpha_raw, alpha_bias, aw);
        elman_scan_kernel<true><<<1024, 256, 0, stream>>>(
            B_proj, X_proj, aw, alpha_bias, H0, out, Hf);
    } else {
        elman_scan_kernel<false><<<1024, 256, 0, stream>>>(
            B_proj, X_proj, alpha_raw, alpha_bias, H0, out, Hf);
    }
    gate_kernel<<<(T * BS * DI / 4) / 256, 256, 0, stream>>>(out, z);
}